// Round 4
// baseline (318.638 us; speedup 1.0000x reference)
//
#include <hip/hip_runtime.h>

typedef __attribute__((ext_vector_type(8))) short bf16x8;
typedef __attribute__((ext_vector_type(8))) _Float16 f16x8;
typedef __attribute__((ext_vector_type(2))) _Float16 f16x2;
typedef __attribute__((ext_vector_type(4))) float f32x4;

__device__ __forceinline__ unsigned short f2bf(float f) {
  union { float f; unsigned int i; } v;
  v.f = f;
  unsigned int r = v.i + 0x7FFFu + ((v.i >> 16) & 1u);  // RNE
  return (unsigned short)(r >> 16);
}

__device__ __forceinline__ f16x2 cvt_pk(float a, float b) {
  return __builtin_bit_cast(f16x2, __builtin_amdgcn_cvt_pkrtz(a, b));
}

// e^x on [-1,1], Chebyshev-truncated degree 5 (abs err ~5e-5), packed f16.
__device__ __forceinline__ f16x2 exp_poly(f16x2 x) {
  const f16x2 a5 = {(_Float16)0.00868682f, (_Float16)0.00868682f};
  const f16x2 a4 = {(_Float16)0.04379392f, (_Float16)0.04379392f};
  const f16x2 a3 = {(_Float16)0.16648887f, (_Float16)0.16648887f};
  const f16x2 a2 = {(_Float16)0.49919676f, (_Float16)0.49919676f};
  const f16x2 a1 = {(_Float16)1.00002229f, (_Float16)1.00002229f};
  const f16x2 a0 = {(_Float16)1.00004478f, (_Float16)1.00004478f};
#if __has_builtin(__builtin_elementwise_fma)
  f16x2 r = a5;
  r = __builtin_elementwise_fma(r, x, a4);
  r = __builtin_elementwise_fma(r, x, a3);
  r = __builtin_elementwise_fma(r, x, a2);
  r = __builtin_elementwise_fma(r, x, a1);
  r = __builtin_elementwise_fma(r, x, a0);
#else
  f16x2 r = a5;
  r = r * x + a4;
  r = r * x + a3;
  r = r * x + a2;
  r = r * x + a1;
  r = r * x + a0;
#endif
  return r;
}

__device__ __forceinline__ float dot2acc(f16x2 a, float acc) {
#if __has_builtin(__builtin_amdgcn_fdot2)
  const f16x2 one2 = {(_Float16)1.0f, (_Float16)1.0f};
  return __builtin_amdgcn_fdot2(a, one2, acc, false);
#else
  return acc + (float)a.x + (float)a.y;
#endif
}

// ---------------- fused fp32 -> bf16 convert for x, Wq, Wkv, Wo ----------------
__global__ __launch_bounds__(256) void cvt_all(
    const float* __restrict__ x, const float* __restrict__ wq,
    const float* __restrict__ wkv, const float* __restrict__ wo,
    unsigned short* __restrict__ xb, unsigned short* __restrict__ wqb,
    unsigned short* __restrict__ wkvb, unsigned short* __restrict__ wob) {
  int b = blockIdx.x;
  const float* in;
  unsigned short* out;
  int i;
  if (b < 8192) { in = x; out = xb; i = b * 256 + threadIdx.x; }
  else if (b < 8448) { in = wq; out = wqb; i = (b - 8192) * 256 + threadIdx.x; }
  else if (b < 8704) { in = wkv; out = wkvb; i = (b - 8448) * 256 + threadIdx.x; }
  else { in = wo; out = wob; i = (b - 8704) * 256 + threadIdx.x; }
  float4 v = ((const float4*)in)[i];
  ushort4 o;
  o.x = f2bf(v.x);
  o.y = f2bf(v.y);
  o.z = f2bf(v.z);
  o.w = f2bf(v.w);
  ((ushort4*)out)[i] = o;
}

// ---------------- fused Q + KV projection GEMM ----------------
// grid (128, 8): y<4 -> Q half (writes Qn bf16, L2-normalized per head),
// y>=4 -> KV half (writes KV f16 raw + Kn bf16 normalized).
__global__ __launch_bounds__(256) void gemm_qkv(
    const unsigned short* __restrict__ A, const unsigned short* __restrict__ Wq,
    const unsigned short* __restrict__ Wkv, const float* __restrict__ bq,
    const float* __restrict__ bkv, unsigned short* __restrict__ Qn,
    _Float16* __restrict__ KV, unsigned short* __restrict__ Kn) {
  __shared__ unsigned short lA[128 * 72];
  __shared__ unsigned short lB[128 * 72];
  const int isKV = (int)(blockIdx.y >> 2);
  const unsigned short* Bt = isKV ? Wkv : Wq;
  const float* bias = isKV ? bkv : bq;
  const int tid = threadIdx.x;
  const int lane = tid & 63;
  const int quad = lane >> 4, m16 = lane & 15;
  const int w = tid >> 6;
  const int wm = w >> 1, wn = w & 1;
  const long mb = (long)blockIdx.x * 128;
  const long nb = (long)(blockIdx.y & 3) * 128;
  f32x4 acc[4][4];
#pragma unroll
  for (int i = 0; i < 4; i++)
#pragma unroll
    for (int j = 0; j < 4; j++) acc[i][j] = (f32x4){0.f, 0.f, 0.f, 0.f};

  for (int kb = 0; kb < 512; kb += 64) {
    __syncthreads();
#pragma unroll
    for (int c = tid; c < 1024; c += 256) {
      int row = c >> 3, k8 = (c & 7) << 3;
      *(uint4*)&lA[row * 72 + k8] = *(const uint4*)(A + (mb + row) * 512 + kb + k8);
      *(uint4*)&lB[row * 72 + k8] = *(const uint4*)(Bt + (nb + row) * 512 + kb + k8);
    }
    __syncthreads();
#pragma unroll
    for (int ks = 0; ks < 64; ks += 32) {
      int kq = ks + quad * 8;
      bf16x8 af[4], bfr[4];
#pragma unroll
      for (int i = 0; i < 4; i++)
        af[i] = *(const bf16x8*)&lA[(wm * 64 + i * 16 + m16) * 72 + kq];
#pragma unroll
      for (int j = 0; j < 4; j++)
        bfr[j] = *(const bf16x8*)&lB[(wn * 64 + j * 16 + m16) * 72 + kq];
#pragma unroll
      for (int i = 0; i < 4; i++)
#pragma unroll
        for (int j = 0; j < 4; j++)
          acc[i][j] =
              __builtin_amdgcn_mfma_f32_16x16x32_bf16(af[i], bfr[j], acc[i][j], 0, 0, 0);
    }
  }
#pragma unroll
  for (int i = 0; i < 4; i++) {
    long row0 = mb + wm * 64 + i * 16 + quad * 4;
    float bb[4], val[4][4];
#pragma unroll
    for (int j = 0; j < 4; j++) {
      bb[j] = bias[nb + wn * 64 + j * 16 + m16];
#pragma unroll
      for (int r = 0; r < 4; r++) val[j][r] = acc[i][j][r] + bb[j];
    }
#pragma unroll
    for (int r = 0; r < 4; r++) {
      float s = val[0][r] * val[0][r] + val[1][r] * val[1][r] +
                val[2][r] * val[2][r] + val[3][r] * val[3][r];
      s += __shfl_xor(s, 1);
      s += __shfl_xor(s, 2);
      s += __shfl_xor(s, 4);
      s += __shfl_xor(s, 8);
      float inv = 1.0f / fmaxf(sqrtf(s), 1e-12f);
#pragma unroll
      for (int j = 0; j < 4; j++) {
        long col = nb + wn * 64 + j * 16 + m16;
        long idx = (row0 + r) * 512 + col;
        if (isKV) {
          KV[idx] = (_Float16)val[j][r];
          Kn[idx] = f2bf(val[j][r] * inv);
        } else {
          Qn[idx] = f2bf(val[j][r] * inv);
        }
      }
    }
  }
}

// ---------------- output projection GEMM (bf16 in, f32 out) ----------------
__global__ __launch_bounds__(256) void gemm_o(
    const unsigned short* __restrict__ A, const unsigned short* __restrict__ Bt,
    const float* __restrict__ bias, float* __restrict__ Cout) {
  __shared__ unsigned short lA[128 * 72];
  __shared__ unsigned short lB[128 * 72];
  const int tid = threadIdx.x;
  const int lane = tid & 63;
  const int quad = lane >> 4, m16 = lane & 15;
  const int w = tid >> 6;
  const int wm = w >> 1, wn = w & 1;
  const long mb = (long)blockIdx.x * 128;
  const long nb = (long)blockIdx.y * 128;
  f32x4 acc[4][4];
#pragma unroll
  for (int i = 0; i < 4; i++)
#pragma unroll
    for (int j = 0; j < 4; j++) acc[i][j] = (f32x4){0.f, 0.f, 0.f, 0.f};

  for (int kb = 0; kb < 512; kb += 64) {
    __syncthreads();
#pragma unroll
    for (int c = tid; c < 1024; c += 256) {
      int row = c >> 3, k8 = (c & 7) << 3;
      *(uint4*)&lA[row * 72 + k8] = *(const uint4*)(A + (mb + row) * 512 + kb + k8);
      *(uint4*)&lB[row * 72 + k8] = *(const uint4*)(Bt + (nb + row) * 512 + kb + k8);
    }
    __syncthreads();
#pragma unroll
    for (int ks = 0; ks < 64; ks += 32) {
      int kq = ks + quad * 8;
      bf16x8 af[4], bfr[4];
#pragma unroll
      for (int i = 0; i < 4; i++)
        af[i] = *(const bf16x8*)&lA[(wm * 64 + i * 16 + m16) * 72 + kq];
#pragma unroll
      for (int j = 0; j < 4; j++)
        bfr[j] = *(const bf16x8*)&lB[(wn * 64 + j * 16 + m16) * 72 + kq];
#pragma unroll
      for (int i = 0; i < 4; i++)
#pragma unroll
        for (int j = 0; j < 4; j++)
          acc[i][j] =
              __builtin_amdgcn_mfma_f32_16x16x32_bf16(af[i], bfr[j], acc[i][j], 0, 0, 0);
    }
  }
#pragma unroll
  for (int i = 0; i < 4; i++) {
    long row0 = mb + wm * 64 + i * 16 + quad * 4;
#pragma unroll
    for (int j = 0; j < 4; j++) {
      long col = nb + wn * 64 + j * 16 + m16;
      float bb = bias[col];
#pragma unroll
      for (int r = 0; r < 4; r++) Cout[(row0 + r) * 512 + col] = acc[i][j][r] + bb;
    }
  }
}

// ---------------- V transpose: KV[s][512] -> Vt[g=64][d=64][s=2048] ----------------
__global__ __launch_bounds__(256) void transpose_v(
    const unsigned short* __restrict__ KV, unsigned short* __restrict__ Vt) {
  __shared__ unsigned short t[64 * 72];
  const int st = blockIdx.x;  // s-tile 0..31
  const int g = blockIdx.y;   // 0..63
  const int bm = g >> 3, h = g & 7;
  const int tid = threadIdx.x;
#pragma unroll
  for (int p = 0; p < 2; ++p) {
    int c = tid + p * 256;
    int s = c >> 3, d8 = (c & 7) << 3;
    int dsw = d8 ^ (((s >> 3) & 7) << 3);
    *(uint4*)&t[s * 72 + dsw] =
        *(const uint4*)(KV + ((long)bm * 2048 + st * 64 + s) * 512 + h * 64 + d8);
  }
  __syncthreads();
#pragma unroll
  for (int p = 0; p < 2; ++p) {
    int c = tid + p * 256;
    int d = c >> 3, s8 = (c & 7) << 3;
    int swz = (c & 7) << 3;
    unsigned short v[8];
#pragma unroll
    for (int j = 0; j < 8; ++j) v[j] = t[(s8 + j) * 72 + (d ^ swz)];
    *(uint4*)(Vt + ((long)g * 64 + d) * 2048 + st * 64 + s8) = *(uint4*)v;
  }
}

// ---------------- cosine attention ----------------
// S^T = Kn @ Qn^T (bf16 MFMA) -> packed-f16 poly exp -> PV in f16 MFMA.
// Register-prefetched K/V staging; lP rows wave-private (no extra barrier).
__global__ __launch_bounds__(256, 4) void attn_cos(
    const unsigned short* __restrict__ Qn, const unsigned short* __restrict__ Kn,
    const unsigned short* __restrict__ Vt, unsigned short* __restrict__ ctx) {
  __shared__ unsigned short lK[64 * 72];   // Kn tile [k][d]  bf16
  __shared__ unsigned short lVt[64 * 72];  // V^T tile [d][k] f16
  __shared__ unsigned short lP[128 * 72];  // P [q][k] f16, wave-private rows
  const int qt = blockIdx.x;  // 0..15
  const int g = blockIdx.y;   // 0..63
  const int bm = g >> 3, h = g & 7;
  const int tid = threadIdx.x;
  const int lane = tid & 63;
  const int quad = lane >> 4, m16 = lane & 15;
  const int w = tid >> 6;
  const long rowbase = (long)bm * 2048;
  const int colbase = h * 64;
  const long qrow0 = rowbase + qt * 128 + w * 32;
  const unsigned short* Kbase = Kn + rowbase * 512 + colbase;
  const unsigned short* Vbase = Vt + (long)g * 64 * 2048;
  const int srow = tid >> 3;        // 0..31 (p adds 32)
  const int se8 = (tid & 7) << 3;

  // Q B-fragments (fixed for all k-tiles)
  bf16x8 qf[2][2];
#pragma unroll
  for (int i = 0; i < 2; i++)
#pragma unroll
    for (int ks = 0; ks < 2; ks++)
      qf[i][ks] = *(const bf16x8*)(Qn + (qrow0 + i * 16 + m16) * 512 + colbase +
                                   ks * 32 + quad * 8);

  // prefetch tile 0
  uint4 rK[2], rV[2];
#pragma unroll
  for (int p = 0; p < 2; ++p) {
    int row = srow + p * 32;
    rK[p] = *(const uint4*)(Kbase + row * 512 + se8);
    rV[p] = *(const uint4*)(Vbase + row * 2048 + se8);
  }

  f32x4 cacc[2][4];
#pragma unroll
  for (int i = 0; i < 2; i++)
#pragma unroll
    for (int j = 0; j < 4; j++) cacc[i][j] = (f32x4){0.f, 0.f, 0.f, 0.f};
  float li[2] = {0.f, 0.f};

  for (int kt = 0; kt < 32; ++kt) {
    __syncthreads();
#pragma unroll
    for (int p = 0; p < 2; ++p) {
      int row = srow + p * 32;
      *(uint4*)&lK[row * 72 + se8] = rK[p];
      *(uint4*)&lVt[row * 72 + se8] = rV[p];
    }
    __syncthreads();
    if (kt < 31) {
#pragma unroll
      for (int p = 0; p < 2; ++p) {
        int row = srow + p * 32;
        rK[p] = *(const uint4*)(Kbase + ((kt + 1) * 64 + row) * 512 + se8);
        rV[p] = *(const uint4*)(Vbase + row * 2048 + (kt + 1) * 64 + se8);
      }
    }

    // S^T[k][q]: A = Kn frag (m=k), B = Q frag (n=q), contraction d=64
    f32x4 sacc[4][2];
#pragma unroll
    for (int j = 0; j < 4; j++)
#pragma unroll
      for (int i = 0; i < 2; i++) sacc[j][i] = (f32x4){0.f, 0.f, 0.f, 0.f};
#pragma unroll
    for (int ks = 0; ks < 2; ++ks) {
      int dq = ks * 32 + quad * 8;
      bf16x8 kf[4];
#pragma unroll
      for (int j = 0; j < 4; j++)
        kf[j] = *(const bf16x8*)&lK[(j * 16 + m16) * 72 + dq];
#pragma unroll
      for (int j = 0; j < 4; j++)
#pragma unroll
        for (int i = 0; i < 2; i++)
          sacc[j][i] =
              __builtin_amdgcn_mfma_f32_16x16x32_bf16(kf[j], qf[i][ks], sacc[j][i], 0, 0, 0);
    }

    // packed-f16 exp + li + P write. Lane: q = i*16+m16, k = j*16+quad*4+(0..3)
#pragma unroll
    for (int j = 0; j < 4; j++)
#pragma unroll
      for (int i = 0; i < 2; i++) {
        f16x2 x01 = cvt_pk(sacc[j][i][0], sacc[j][i][1]);
        f16x2 x23 = cvt_pk(sacc[j][i][2], sacc[j][i][3]);
        f16x2 e01 = exp_poly(x01);
        f16x2 e23 = exp_poly(x23);
        li[i] = dot2acc(e01, li[i]);
        li[i] = dot2acc(e23, li[i]);
        uint2 pk = make_uint2(__builtin_bit_cast(unsigned int, e01),
                              __builtin_bit_cast(unsigned int, e23));
        *(uint2*)&lP[(w * 32 + i * 16 + m16) * 72 + j * 16 + quad * 4] = pk;
      }

    // PV (f16): ctx[q][d] += P @ V, contraction k=64
#pragma unroll
    for (int ks = 0; ks < 2; ++ks) {
      int kq = ks * 32 + quad * 8;
      f16x8 pf[2], vf[4];
#pragma unroll
      for (int i = 0; i < 2; i++)
        pf[i] = *(const f16x8*)&lP[(w * 32 + i * 16 + m16) * 72 + kq];
#pragma unroll
      for (int j = 0; j < 4; j++)
        vf[j] = *(const f16x8*)&lVt[(j * 16 + m16) * 72 + kq];
#pragma unroll
      for (int i = 0; i < 2; i++)
#pragma unroll
        for (int j = 0; j < 4; j++)
          cacc[i][j] =
              __builtin_amdgcn_mfma_f32_16x16x32_f16(pf[i], vf[j], cacc[i][j], 0, 0, 0);
    }
  }

  // reduce li across quads (lanes sharing m16)
#pragma unroll
  for (int i = 0; i < 2; i++) {
    li[i] += __shfl_xor(li[i], 16);
    li[i] += __shfl_xor(li[i], 32);
  }
  float linv[2][4];
#pragma unroll
  for (int i = 0; i < 2; i++)
#pragma unroll
    for (int r = 0; r < 4; r++) linv[i][r] = 1.0f / __shfl(li[i], quad * 4 + r);
#pragma unroll
  for (int i = 0; i < 2; i++)
#pragma unroll
    for (int j = 0; j < 4; j++) {
      long dcol = colbase + j * 16 + m16;
#pragma unroll
      for (int r = 0; r < 4; r++) {
        long qrow = qrow0 + i * 16 + quad * 4 + r;
        ctx[qrow * 512 + dcol] = f2bf(cacc[i][j][r] * linv[i][r]);
      }
    }
}

extern "C" void kernel_launch(void* const* d_in, const int* in_sizes, int n_in,
                              void* d_out, int out_size, void* d_ws, size_t ws_size,
                              hipStream_t stream) {
  (void)in_sizes; (void)n_in; (void)out_size; (void)ws_size;
  const float* x = (const float*)d_in[0];
  const float* Wq = (const float*)d_in[1];
  const float* bq = (const float*)d_in[2];
  const float* Wkv = (const float*)d_in[3];
  const float* bkv = (const float*)d_in[4];
  const float* Wo = (const float*)d_in[5];
  const float* bo = (const float*)d_in[6];

  char* ws = (char*)d_ws;
  unsigned short* x_bf   = (unsigned short*)(ws);             // 16 MiB (reused as ctx)
  unsigned short* Wq_bf  = (unsigned short*)(ws + 16777216);  // 512 KiB
  unsigned short* Wkv_bf = (unsigned short*)(ws + 17301504);  // 512 KiB
  unsigned short* Wo_bf  = (unsigned short*)(ws + 17825792);  // 512 KiB
  unsigned short* Qn_bf  = (unsigned short*)(ws + 18350080);  // 16 MiB
  unsigned short* KV_f16 = (unsigned short*)(ws + 35127296);  // 16 MiB (V, f16)
  unsigned short* Kn_bf  = (unsigned short*)(ws + 51904512);  // 16 MiB
  unsigned short* Vt_f16 = (unsigned short*)(ws + 68681728);  // 16 MiB
  unsigned short* ctx_bf = x_bf;  // x dead after gemm_qkv

  cvt_all<<<8960, 256, 0, stream>>>(x, Wq, Wkv, Wo, x_bf, Wq_bf, Wkv_bf, Wo_bf);

  gemm_qkv<<<dim3(128, 8), 256, 0, stream>>>(x_bf, Wq_bf, Wkv_bf, bq, bkv, Qn_bf,
                                             (_Float16*)KV_f16, Kn_bf);

  transpose_v<<<dim3(32, 64), 256, 0, stream>>>(KV_f16, Vt_f16);

  attn_cos<<<dim3(16, 64), 256, 0, stream>>>(Qn_bf, Kn_bf, Vt_f16, ctx_bf);

  gemm_o<<<dim3(128, 4), 256, 0, stream>>>(ctx_bf, Wo_bf, bo, (float*)d_out);
}

// Round 5
// 252.032 us; speedup vs baseline: 1.2643x; 1.2643x over previous
//
#include <hip/hip_runtime.h>

typedef __attribute__((ext_vector_type(8))) short bf16x8;
typedef __attribute__((ext_vector_type(8))) _Float16 f16x8;
typedef __attribute__((ext_vector_type(2))) _Float16 f16x2;
typedef __attribute__((ext_vector_type(4))) float f32x4;

__device__ __forceinline__ unsigned short f2bf(float f) {
  union { float f; unsigned int i; } v;
  v.f = f;
  unsigned int r = v.i + 0x7FFFu + ((v.i >> 16) & 1u);  // RNE
  return (unsigned short)(r >> 16);
}

__device__ __forceinline__ f16x2 cvt_pk(float a, float b) {
  return __builtin_bit_cast(f16x2, __builtin_amdgcn_cvt_pkrtz(a, b));
}

// e^x on [-1,1], Chebyshev-truncated degree 5 (abs err ~5e-5), packed f16.
__device__ __forceinline__ f16x2 exp_poly(f16x2 x) {
  const f16x2 a5 = {(_Float16)0.00868682f, (_Float16)0.00868682f};
  const f16x2 a4 = {(_Float16)0.04379392f, (_Float16)0.04379392f};
  const f16x2 a3 = {(_Float16)0.16648887f, (_Float16)0.16648887f};
  const f16x2 a2 = {(_Float16)0.49919676f, (_Float16)0.49919676f};
  const f16x2 a1 = {(_Float16)1.00002229f, (_Float16)1.00002229f};
  const f16x2 a0 = {(_Float16)1.00004478f, (_Float16)1.00004478f};
#if __has_builtin(__builtin_elementwise_fma)
  f16x2 r = a5;
  r = __builtin_elementwise_fma(r, x, a4);
  r = __builtin_elementwise_fma(r, x, a3);
  r = __builtin_elementwise_fma(r, x, a2);
  r = __builtin_elementwise_fma(r, x, a1);
  r = __builtin_elementwise_fma(r, x, a0);
#else
  f16x2 r = a5;
  r = r * x + a4;
  r = r * x + a3;
  r = r * x + a2;
  r = r * x + a1;
  r = r * x + a0;
#endif
  return r;
}

__device__ __forceinline__ float dot2acc(f16x2 a, float acc) {
#if __has_builtin(__builtin_amdgcn_fdot2)
  const f16x2 one2 = {(_Float16)1.0f, (_Float16)1.0f};
  return __builtin_amdgcn_fdot2(a, one2, acc, false);
#else
  return acc + (float)a.x + (float)a.y;
#endif
}

// ---------------- fused fp32 -> bf16 convert for x, Wq, Wkv, Wo ----------------
__global__ __launch_bounds__(256) void cvt_all(
    const float* __restrict__ x, const float* __restrict__ wq,
    const float* __restrict__ wkv, const float* __restrict__ wo,
    unsigned short* __restrict__ xb, unsigned short* __restrict__ wqb,
    unsigned short* __restrict__ wkvb, unsigned short* __restrict__ wob) {
  int b = blockIdx.x;
  const float* in;
  unsigned short* out;
  int i;
  if (b < 8192) { in = x; out = xb; i = b * 256 + threadIdx.x; }
  else if (b < 8448) { in = wq; out = wqb; i = (b - 8192) * 256 + threadIdx.x; }
  else if (b < 8704) { in = wkv; out = wkvb; i = (b - 8448) * 256 + threadIdx.x; }
  else { in = wo; out = wob; i = (b - 8704) * 256 + threadIdx.x; }
  float4 v = ((const float4*)in)[i];
  ushort4 o;
  o.x = f2bf(v.x);
  o.y = f2bf(v.y);
  o.z = f2bf(v.z);
  o.w = f2bf(v.w);
  ((ushort4*)out)[i] = o;
}

// ---------------- fused Q + KV projection GEMM ----------------
// grid (128, 8): y<4 -> Q half (writes Qn bf16, L2-normalized per head),
// y>=4 -> KV half (writes Kn bf16 normalized + Vt f16 transposed
// [g=64][d=64][s=2048] directly from the accumulator — no transpose kernel).
__global__ __launch_bounds__(256) void gemm_qkv(
    const unsigned short* __restrict__ A, const unsigned short* __restrict__ Wq,
    const unsigned short* __restrict__ Wkv, const float* __restrict__ bq,
    const float* __restrict__ bkv, unsigned short* __restrict__ Qn,
    unsigned short* __restrict__ Vt, unsigned short* __restrict__ Kn) {
  __shared__ unsigned short lA[128 * 72];
  __shared__ unsigned short lB[128 * 72];
  const int isKV = (int)(blockIdx.y >> 2);
  const unsigned short* Bt = isKV ? Wkv : Wq;
  const float* bias = isKV ? bkv : bq;
  const int tid = threadIdx.x;
  const int lane = tid & 63;
  const int quad = lane >> 4, m16 = lane & 15;
  const int w = tid >> 6;
  const int wm = w >> 1, wn = w & 1;
  const long mb = (long)blockIdx.x * 128;
  const long nb = (long)(blockIdx.y & 3) * 128;
  f32x4 acc[4][4];
#pragma unroll
  for (int i = 0; i < 4; i++)
#pragma unroll
    for (int j = 0; j < 4; j++) acc[i][j] = (f32x4){0.f, 0.f, 0.f, 0.f};

  for (int kb = 0; kb < 512; kb += 64) {
    __syncthreads();
#pragma unroll
    for (int c = tid; c < 1024; c += 256) {
      int row = c >> 3, k8 = (c & 7) << 3;
      *(uint4*)&lA[row * 72 + k8] = *(const uint4*)(A + (mb + row) * 512 + kb + k8);
      *(uint4*)&lB[row * 72 + k8] = *(const uint4*)(Bt + (nb + row) * 512 + kb + k8);
    }
    __syncthreads();
#pragma unroll
    for (int ks = 0; ks < 64; ks += 32) {
      int kq = ks + quad * 8;
      bf16x8 af[4], bfr[4];
#pragma unroll
      for (int i = 0; i < 4; i++)
        af[i] = *(const bf16x8*)&lA[(wm * 64 + i * 16 + m16) * 72 + kq];
#pragma unroll
      for (int j = 0; j < 4; j++)
        bfr[j] = *(const bf16x8*)&lB[(wn * 64 + j * 16 + m16) * 72 + kq];
#pragma unroll
      for (int i = 0; i < 4; i++)
#pragma unroll
        for (int j = 0; j < 4; j++)
          acc[i][j] =
              __builtin_amdgcn_mfma_f32_16x16x32_bf16(af[i], bfr[j], acc[i][j], 0, 0, 0);
    }
  }
#pragma unroll
  for (int i = 0; i < 4; i++) {
    long row0 = mb + wm * 64 + i * 16 + quad * 4;
    float bb[4], val[4][4], inv[4];
#pragma unroll
    for (int j = 0; j < 4; j++) {
      bb[j] = bias[nb + wn * 64 + j * 16 + m16];
#pragma unroll
      for (int r = 0; r < 4; r++) val[j][r] = acc[i][j][r] + bb[j];
    }
#pragma unroll
    for (int r = 0; r < 4; r++) {
      float s = val[0][r] * val[0][r] + val[1][r] * val[1][r] +
                val[2][r] * val[2][r] + val[3][r] * val[3][r];
      s += __shfl_xor(s, 1);
      s += __shfl_xor(s, 2);
      s += __shfl_xor(s, 4);
      s += __shfl_xor(s, 8);
      inv[r] = 1.0f / fmaxf(sqrtf(s), 1e-12f);
    }
    if (!isKV) {
#pragma unroll
      for (int r = 0; r < 4; r++)
#pragma unroll
        for (int j = 0; j < 4; j++) {
          long col = nb + wn * 64 + j * 16 + m16;
          Qn[(row0 + r) * 512 + col] = f2bf(val[j][r] * inv[r]);
        }
    } else {
#pragma unroll
      for (int r = 0; r < 4; r++)
#pragma unroll
        for (int j = 0; j < 4; j++) {
          long col = nb + wn * 64 + j * 16 + m16;
          Kn[(row0 + r) * 512 + col] = f2bf(val[j][r] * inv[r]);
        }
      // V^T: 4 consecutive s per lane for fixed (g,d) -> one 8B f16 store
      int bm = (int)(row0 >> 11);
      int s0 = (int)(row0 & 2047);
#pragma unroll
      for (int j = 0; j < 4; j++) {
        int col = (int)(nb) + wn * 64 + j * 16 + m16;
        int h = col >> 6, d = col & 63;
        f16x2 lo = cvt_pk(val[j][0], val[j][1]);
        f16x2 hi = cvt_pk(val[j][2], val[j][3]);
        uint2 pk = make_uint2(__builtin_bit_cast(unsigned int, lo),
                              __builtin_bit_cast(unsigned int, hi));
        *(uint2*)(Vt + ((long)(bm * 8 + h) * 64 + d) * 2048 + s0) = pk;
      }
    }
  }
}

// ---------------- output projection GEMM (bf16 in, f32 out) ----------------
__global__ __launch_bounds__(256) void gemm_o(
    const unsigned short* __restrict__ A, const unsigned short* __restrict__ Bt,
    const float* __restrict__ bias, float* __restrict__ Cout) {
  __shared__ unsigned short lA[128 * 72];
  __shared__ unsigned short lB[128 * 72];
  const int tid = threadIdx.x;
  const int lane = tid & 63;
  const int quad = lane >> 4, m16 = lane & 15;
  const int w = tid >> 6;
  const int wm = w >> 1, wn = w & 1;
  const long mb = (long)blockIdx.x * 128;
  const long nb = (long)blockIdx.y * 128;
  f32x4 acc[4][4];
#pragma unroll
  for (int i = 0; i < 4; i++)
#pragma unroll
    for (int j = 0; j < 4; j++) acc[i][j] = (f32x4){0.f, 0.f, 0.f, 0.f};

  for (int kb = 0; kb < 512; kb += 64) {
    __syncthreads();
#pragma unroll
    for (int c = tid; c < 1024; c += 256) {
      int row = c >> 3, k8 = (c & 7) << 3;
      *(uint4*)&lA[row * 72 + k8] = *(const uint4*)(A + (mb + row) * 512 + kb + k8);
      *(uint4*)&lB[row * 72 + k8] = *(const uint4*)(Bt + (nb + row) * 512 + kb + k8);
    }
    __syncthreads();
#pragma unroll
    for (int ks = 0; ks < 64; ks += 32) {
      int kq = ks + quad * 8;
      bf16x8 af[4], bfr[4];
#pragma unroll
      for (int i = 0; i < 4; i++)
        af[i] = *(const bf16x8*)&lA[(wm * 64 + i * 16 + m16) * 72 + kq];
#pragma unroll
      for (int j = 0; j < 4; j++)
        bfr[j] = *(const bf16x8*)&lB[(wn * 64 + j * 16 + m16) * 72 + kq];
#pragma unroll
      for (int i = 0; i < 4; i++)
#pragma unroll
        for (int j = 0; j < 4; j++)
          acc[i][j] =
              __builtin_amdgcn_mfma_f32_16x16x32_bf16(af[i], bfr[j], acc[i][j], 0, 0, 0);
    }
  }
#pragma unroll
  for (int i = 0; i < 4; i++) {
    long row0 = mb + wm * 64 + i * 16 + quad * 4;
#pragma unroll
    for (int j = 0; j < 4; j++) {
      long col = nb + wn * 64 + j * 16 + m16;
      float bb = bias[col];
#pragma unroll
      for (int r = 0; r < 4; r++) Cout[(row0 + r) * 512 + col] = acc[i][j][r] + bb;
    }
  }
}

// ---------------- cosine attention ----------------
// S^T = Kn @ Qn^T (bf16 MFMA) -> packed-f16 poly exp -> PV in f16 MFMA.
// Direct synchronous staging (NO register prefetch — it spilled to scratch
// in R4: 484 MB of scratch writes). lP rows wave-private (no extra barrier).
__global__ __launch_bounds__(256, 4) void attn_cos(
    const unsigned short* __restrict__ Qn, const unsigned short* __restrict__ Kn,
    const unsigned short* __restrict__ Vt, unsigned short* __restrict__ ctx) {
  __shared__ unsigned short lK[64 * 72];   // Kn tile [k][d]  bf16
  __shared__ unsigned short lVt[64 * 72];  // V^T tile [d][k] f16
  __shared__ unsigned short lP[128 * 72];  // P [q][k] f16, wave-private rows
  const int qt = blockIdx.x;  // 0..15
  const int g = blockIdx.y;   // 0..63
  const int bm = g >> 3, h = g & 7;
  const int tid = threadIdx.x;
  const int lane = tid & 63;
  const int quad = lane >> 4, m16 = lane & 15;
  const int w = tid >> 6;
  const long rowbase = (long)bm * 2048;
  const int colbase = h * 64;
  const long qrow0 = rowbase + qt * 128 + w * 32;
  const unsigned short* Kbase = Kn + rowbase * 512 + colbase;
  const unsigned short* Vbase = Vt + (long)g * 64 * 2048;

  // Q B-fragments (fixed for all k-tiles)
  bf16x8 qf[2][2];
#pragma unroll
  for (int i = 0; i < 2; i++)
#pragma unroll
    for (int ks = 0; ks < 2; ks++)
      qf[i][ks] = *(const bf16x8*)(Qn + (qrow0 + i * 16 + m16) * 512 + colbase +
                                   ks * 32 + quad * 8);

  f32x4 cacc[2][4];
#pragma unroll
  for (int i = 0; i < 2; i++)
#pragma unroll
    for (int j = 0; j < 4; j++) cacc[i][j] = (f32x4){0.f, 0.f, 0.f, 0.f};
  float li[2] = {0.f, 0.f};

  for (int kt = 0; kt < 32; ++kt) {
    __syncthreads();
#pragma unroll
    for (int p = 0; p < 2; ++p) {
      int c = tid + p * 256;  // 0..511
      int row = c >> 3, e8 = (c & 7) << 3;
      *(uint4*)&lK[row * 72 + e8] = *(const uint4*)(Kbase + (kt * 64 + row) * 512 + e8);
      *(uint4*)&lVt[row * 72 + e8] = *(const uint4*)(Vbase + row * 2048 + kt * 64 + e8);
    }
    __syncthreads();

    // S^T[k][q]: A = Kn frag (m=k), B = Q frag (n=q), contraction d=64
    f32x4 sacc[4][2];
#pragma unroll
    for (int j = 0; j < 4; j++)
#pragma unroll
      for (int i = 0; i < 2; i++) sacc[j][i] = (f32x4){0.f, 0.f, 0.f, 0.f};
#pragma unroll
    for (int ks = 0; ks < 2; ++ks) {
      int dq = ks * 32 + quad * 8;
      bf16x8 kf[4];
#pragma unroll
      for (int j = 0; j < 4; j++)
        kf[j] = *(const bf16x8*)&lK[(j * 16 + m16) * 72 + dq];
#pragma unroll
      for (int j = 0; j < 4; j++)
#pragma unroll
        for (int i = 0; i < 2; i++)
          sacc[j][i] =
              __builtin_amdgcn_mfma_f32_16x16x32_bf16(kf[j], qf[i][ks], sacc[j][i], 0, 0, 0);
    }

    // packed-f16 exp + li + P write. Lane: q = i*16+m16, k = j*16+quad*4+(0..3)
#pragma unroll
    for (int j = 0; j < 4; j++)
#pragma unroll
      for (int i = 0; i < 2; i++) {
        f16x2 x01 = cvt_pk(sacc[j][i][0], sacc[j][i][1]);
        f16x2 x23 = cvt_pk(sacc[j][i][2], sacc[j][i][3]);
        f16x2 e01 = exp_poly(x01);
        f16x2 e23 = exp_poly(x23);
        li[i] = dot2acc(e01, li[i]);
        li[i] = dot2acc(e23, li[i]);
        uint2 pk = make_uint2(__builtin_bit_cast(unsigned int, e01),
                              __builtin_bit_cast(unsigned int, e23));
        *(uint2*)&lP[(w * 32 + i * 16 + m16) * 72 + j * 16 + quad * 4] = pk;
      }

    // PV (f16): ctx[q][d] += P @ V, contraction k=64
#pragma unroll
    for (int ks = 0; ks < 2; ++ks) {
      int kq = ks * 32 + quad * 8;
      f16x8 pf[2], vf[4];
#pragma unroll
      for (int i = 0; i < 2; i++)
        pf[i] = *(const f16x8*)&lP[(w * 32 + i * 16 + m16) * 72 + kq];
#pragma unroll
      for (int j = 0; j < 4; j++)
        vf[j] = *(const f16x8*)&lVt[(j * 16 + m16) * 72 + kq];
#pragma unroll
      for (int i = 0; i < 2; i++)
#pragma unroll
        for (int j = 0; j < 4; j++)
          cacc[i][j] =
              __builtin_amdgcn_mfma_f32_16x16x32_f16(pf[i], vf[j], cacc[i][j], 0, 0, 0);
    }
  }

  // reduce li across quads (lanes sharing m16)
#pragma unroll
  for (int i = 0; i < 2; i++) {
    li[i] += __shfl_xor(li[i], 16);
    li[i] += __shfl_xor(li[i], 32);
  }
  float linv[2][4];
#pragma unroll
  for (int i = 0; i < 2; i++)
#pragma unroll
    for (int r = 0; r < 4; r++) linv[i][r] = 1.0f / __shfl(li[i], quad * 4 + r);
#pragma unroll
  for (int i = 0; i < 2; i++)
#pragma unroll
    for (int j = 0; j < 4; j++) {
      long dcol = colbase + j * 16 + m16;
#pragma unroll
      for (int r = 0; r < 4; r++) {
        long qrow = qrow0 + i * 16 + quad * 4 + r;
        ctx[qrow * 512 + dcol] = f2bf(cacc[i][j][r] * linv[i][r]);
      }
    }
}

extern "C" void kernel_launch(void* const* d_in, const int* in_sizes, int n_in,
                              void* d_out, int out_size, void* d_ws, size_t ws_size,
                              hipStream_t stream) {
  (void)in_sizes; (void)n_in; (void)out_size; (void)ws_size;
  const float* x = (const float*)d_in[0];
  const float* Wq = (const float*)d_in[1];
  const float* bq = (const float*)d_in[2];
  const float* Wkv = (const float*)d_in[3];
  const float* bkv = (const float*)d_in[4];
  const float* Wo = (const float*)d_in[5];
  const float* bo = (const float*)d_in[6];

  char* ws = (char*)d_ws;
  unsigned short* x_bf   = (unsigned short*)(ws);             // 16 MiB (reused as ctx)
  unsigned short* Wq_bf  = (unsigned short*)(ws + 16777216);  // 512 KiB
  unsigned short* Wkv_bf = (unsigned short*)(ws + 17301504);  // 512 KiB
  unsigned short* Wo_bf  = (unsigned short*)(ws + 17825792);  // 512 KiB
  unsigned short* Qn_bf  = (unsigned short*)(ws + 18350080);  // 16 MiB
  unsigned short* Kn_bf  = (unsigned short*)(ws + 35127296);  // 16 MiB
  unsigned short* Vt_f16 = (unsigned short*)(ws + 51904512);  // 16 MiB
  unsigned short* ctx_bf = x_bf;  // x dead after gemm_qkv

  cvt_all<<<8960, 256, 0, stream>>>(x, Wq, Wkv, Wo, x_bf, Wq_bf, Wkv_bf, Wo_bf);

  gemm_qkv<<<dim3(128, 8), 256, 0, stream>>>(x_bf, Wq_bf, Wkv_bf, bq, bkv, Qn_bf,
                                             Vt_f16, Kn_bf);

  attn_cos<<<dim3(16, 64), 256, 0, stream>>>(Qn_bf, Kn_bf, Vt_f16, ctx_bf);

  gemm_o<<<dim3(128, 4), 256, 0, stream>>>(ctx_bf, Wo_bf, bo, (float*)d_out);
}